// Round 7
// baseline (206.368 us; speedup 1.0000x reference)
//
#include <hip/hip_runtime.h>
#include <hip/hip_bf16.h>
#include <stdint.h>

typedef short bf16x8 __attribute__((ext_vector_type(8)));
typedef float f32x4 __attribute__((ext_vector_type(4)));
typedef unsigned u32x2 __attribute__((ext_vector_type(2)));

#define MFMA_BF16(a, b, c) __builtin_amdgcn_mfma_f32_16x16x32_bf16((a), (b), (c), 0, 0, 0)

#define GLOAD_LDS16(g, l) __builtin_amdgcn_global_load_lds( \
    (const __attribute__((address_space(1))) void*)(g),     \
    (__attribute__((address_space(3))) void*)(l), 16, 0, 0)

__device__ __forceinline__ unsigned short f2bf(float f) {
    union { float f; unsigned u; } v; v.f = f;
    unsigned r = v.u + 0x7FFFu + ((v.u >> 16) & 1u);  // RNE
    return (unsigned short)(r >> 16);
}

__device__ __forceinline__ unsigned cvt_pk_bf16(float a, float b) {
    unsigned r;
    asm("v_cvt_pk_bf16_f32 %0, %1, %2" : "=v"(r) : "v"(a), "v"(b));
    return r;  // low16 = bf16(a), high16 = bf16(b), RNE
}

// ---------------- fp32 -> bf16 convert, 3 tensors in one launch ----------------
__global__ void cvt3_kernel(const float* __restrict__ i0, const float* __restrict__ i1,
                            const float* __restrict__ i2,
                            unsigned short* __restrict__ o0, unsigned short* __restrict__ o1,
                            unsigned short* __restrict__ o2, int n4) {
    const int z = blockIdx.y;
    const float* in = z == 0 ? i0 : (z == 1 ? i1 : i2);
    unsigned short* out = z == 0 ? o0 : (z == 1 ? o1 : o2);
    int i = blockIdx.x * blockDim.x + threadIdx.x;
    if (i >= n4) return;
    float4 v = ((const float4*)in)[i];
    ushort4 o;
    o.x = f2bf(v.x); o.y = f2bf(v.y); o.z = f2bf(v.z); o.w = f2bf(v.w);
    ((ushort4*)out)[i] = o;
}

// ---------------- weight transpose + convert, 4 weights in one launch ----------------
__global__ void wtrans4_kernel(const float* __restrict__ w0, const float* __restrict__ w1,
                               const float* __restrict__ w2, const float* __restrict__ w3,
                               unsigned short* __restrict__ t0, unsigned short* __restrict__ t1,
                               unsigned short* __restrict__ t2, unsigned short* __restrict__ t3) {
    __shared__ float tile[32][33];
    const int z = blockIdx.z;
    const float* w = z == 0 ? w0 : (z == 1 ? w1 : (z == 2 ? w2 : w3));
    unsigned short* wt = z == 0 ? t0 : (z == 1 ? t1 : (z == 2 ? t2 : t3));
    const int tx = threadIdx.x, ty = threadIdx.y;
    const int bx = blockIdx.x, by = blockIdx.y;
#pragma unroll
    for (int i = 0; i < 4; ++i)
        tile[ty + 8 * i][tx] = w[(size_t)(by * 32 + ty + 8 * i) * 1024 + bx * 32 + tx];
    __syncthreads();
#pragma unroll
    for (int i = 0; i < 4; ++i)
        wt[(size_t)(bx * 32 + ty + 8 * i) * 1024 + by * 32 + tx] = f2bf(tile[tx][ty + 8 * i]);
}

// ---------------- fused QKV GEMM, BM=128 BN=64: z=0 Q (scaled by log2e/8), z=1 K, z=2 V (transposed) ----------------
__global__ __launch_bounds__(256) void gemm_qkv_kernel(
    const unsigned short* __restrict__ A0, const unsigned short* __restrict__ A1,
    const unsigned short* __restrict__ A2,
    const unsigned short* __restrict__ W0, const unsigned short* __restrict__ W1,
    const unsigned short* __restrict__ W2,
    const float* __restrict__ c0, const float* __restrict__ c1, const float* __restrict__ c2,
    unsigned short* __restrict__ O0, unsigned short* __restrict__ O1,
    unsigned short* __restrict__ O2)
{
    const int z = blockIdx.z;
    const unsigned short* A  = z == 0 ? A0 : (z == 1 ? A1 : A2);
    const unsigned short* Bt = z == 0 ? W0 : (z == 1 ? W1 : W2);
    const float* bias        = z == 0 ? c0 : (z == 1 ? c1 : c2);
    unsigned short* out      = z == 0 ? O0 : (z == 1 ? O1 : O2);
    const float qscale       = z == 0 ? 0.18033688f : 1.0f;   // log2(e)/8

    __shared__ unsigned short As[128 * 64];
    __shared__ unsigned short Bs[64 * 64];
    const int t = threadIdx.x;
    const int lane = t & 63, w = t >> 6;
    const int wr = w >> 1, wc = w & 1;
    const int lr = lane & 15, lg = lane >> 4;
    const int m0 = blockIdx.x * 128, n0 = blockIdx.y * 64;

    f32x4 acc[4][2];
#pragma unroll
    for (int m = 0; m < 4; ++m)
#pragma unroll
        for (int n = 0; n < 2; ++n)
            acc[m][n] = (f32x4){0.f, 0.f, 0.f, 0.f};

    for (int k0 = 0; k0 < 1024; k0 += 64) {
        __syncthreads();
#pragma unroll
        for (int r = 0; r < 4; ++r) {
            int off = r * 4096 + t * 16;
            int row = off >> 7, cb = off & 127;
            GLOAD_LDS16((const char*)A + ((size_t)(m0 + row) * 1024 + k0) * 2 + cb, (char*)As + off);
        }
#pragma unroll
        for (int r = 0; r < 2; ++r) {
            int off = r * 4096 + t * 16;
            int row = off >> 7, cb = off & 127;
            GLOAD_LDS16((const char*)Bt + ((size_t)(n0 + row) * 1024 + k0) * 2 + cb, (char*)Bs + off);
        }
        __syncthreads();
#pragma unroll
        for (int kk = 0; kk < 2; ++kk) {
            bf16x8 af[4], bfr[2];
#pragma unroll
            for (int m = 0; m < 4; ++m)
                af[m] = *(const bf16x8*)&As[(wr * 64 + m * 16 + lr) * 64 + kk * 32 + 8 * lg];
#pragma unroll
            for (int n = 0; n < 2; ++n)
                bfr[n] = *(const bf16x8*)&Bs[(wc * 32 + n * 16 + lr) * 64 + kk * 32 + 8 * lg];
#pragma unroll
            for (int m = 0; m < 4; ++m)
#pragma unroll
                for (int n = 0; n < 2; ++n)
                    acc[m][n] = MFMA_BF16(af[m], bfr[n], acc[m][n]);
        }
    }

#pragma unroll
    for (int m = 0; m < 4; ++m) {
#pragma unroll
        for (int n = 0; n < 2; ++n) {
            const int gn = n0 + wc * 32 + n * 16 + lr;
            const float bv = bias[gn];
#pragma unroll
            for (int r = 0; r < 4; ++r) {
                const int gm = m0 + wr * 64 + m * 16 + lg * 4 + r;
                const float vv = (acc[m][n][r] + bv) * qscale;
                int bi = gm >> 11, pos = gm & 2047, hh = gn >> 6, dh = gn & 63;
                if (z != 2)
                    out[(((size_t)(bi * 16 + hh) * 2048 + pos) << 6) + dh] = f2bf(vv);
                else
                    out[(((size_t)(bi * 16 + hh) * 64 + dh) << 11) + pos] = f2bf(vv);
            }
        }
    }
}

// ---------------- output-projection GEMM, BM=128 BN=64: fp32 out [4096][1024] ----------------
__global__ __launch_bounds__(256) void gemm_o_kernel(
    const unsigned short* __restrict__ A,
    const unsigned short* __restrict__ Bt,
    const float* __restrict__ bias,
    float* __restrict__ out)
{
    __shared__ unsigned short As[128 * 64];
    __shared__ unsigned short Bs[64 * 64];
    const int t = threadIdx.x;
    const int lane = t & 63, w = t >> 6;
    const int wr = w >> 1, wc = w & 1;
    const int lr = lane & 15, lg = lane >> 4;
    const int m0 = blockIdx.x * 128, n0 = blockIdx.y * 64;

    f32x4 acc[4][2];
#pragma unroll
    for (int m = 0; m < 4; ++m)
#pragma unroll
        for (int n = 0; n < 2; ++n)
            acc[m][n] = (f32x4){0.f, 0.f, 0.f, 0.f};

    for (int k0 = 0; k0 < 1024; k0 += 64) {
        __syncthreads();
#pragma unroll
        for (int r = 0; r < 4; ++r) {
            int off = r * 4096 + t * 16;
            int row = off >> 7, cb = off & 127;
            GLOAD_LDS16((const char*)A + ((size_t)(m0 + row) * 1024 + k0) * 2 + cb, (char*)As + off);
        }
#pragma unroll
        for (int r = 0; r < 2; ++r) {
            int off = r * 4096 + t * 16;
            int row = off >> 7, cb = off & 127;
            GLOAD_LDS16((const char*)Bt + ((size_t)(n0 + row) * 1024 + k0) * 2 + cb, (char*)Bs + off);
        }
        __syncthreads();
#pragma unroll
        for (int kk = 0; kk < 2; ++kk) {
            bf16x8 af[4], bfr[2];
#pragma unroll
            for (int m = 0; m < 4; ++m)
                af[m] = *(const bf16x8*)&As[(wr * 64 + m * 16 + lr) * 64 + kk * 32 + 8 * lg];
#pragma unroll
            for (int n = 0; n < 2; ++n)
                bfr[n] = *(const bf16x8*)&Bs[(wc * 32 + n * 16 + lr) * 64 + kk * 32 + 8 * lg];
#pragma unroll
            for (int m = 0; m < 4; ++m)
#pragma unroll
                for (int n = 0; n < 2; ++n)
                    acc[m][n] = MFMA_BF16(af[m], bfr[n], acc[m][n]);
        }
    }

#pragma unroll
    for (int m = 0; m < 4; ++m)
#pragma unroll
        for (int n = 0; n < 2; ++n) {
            const int gn = n0 + wc * 32 + n * 16 + lr;
            const float bv = bias[gn];
#pragma unroll
            for (int r = 0; r < 4; ++r) {
                const int gm = m0 + wr * 64 + m * 16 + lg * 4 + r;
                out[((size_t)gm << 10) + gn] = acc[m][n][r] + bv;
            }
        }
}

// ---------------- flash attention v5: direct-global K/V (L2-resident), no barriers ----------------
// Qh bf16 [B][H][L][64] (pre-scaled by log2e/8); Kh bf16 [B][H][L][64]; Vt bf16 [B][H][64][L]
// AO bf16 [B][L][1024]. grid 512 (XCD-chunk-swizzled), block 256 (4 waves x 32 q-rows).
// No K/V LDS staging: K/V = 512KB/head fits L2; each XCD serves 4 heads (2MB).
// Only per-wave P LDS round-trip remains (chunk-XOR swizzle, conflict-free).
__global__ __launch_bounds__(256, 2) void attn_kernel(
    const unsigned short* __restrict__ Qh,
    const unsigned short* __restrict__ Kh,
    const unsigned short* __restrict__ Vt,
    unsigned short* __restrict__ AO)
{
    __shared__ unsigned short Pl[4][2048];   // per-wave [32 q][64 kv], chunk-XOR-swizzled

    const int flat = blockIdx.x;
    const int orig = (flat & 7) * 64 + (flat >> 3);   // 512 % 8 == 0 -> bijective
    const int qb = orig & 15, h = (orig >> 4) & 15, b = orig >> 8;

    const int t = threadIdx.x;
    const int lane = t & 63, wv = t >> 6;    // 4 waves
    const int lr = lane & 15, lg = lane >> 4;
    const int q0 = qb * 128 + wv * 32;

    const char* Kp = (const char*)(Kh + (((size_t)(b * 16 + h) * 2048) << 6));
    const char* Vp = (const char*)(Vt + (((size_t)(b * 16 + h) * 64) << 11));
    const unsigned short* Qp = Qh + (((size_t)(b * 16 + h) * 2048 + q0) << 6);

    const f32x4 zero4 = {0.f, 0.f, 0.f, 0.f};

    // Q fragments for 2 m-tiles (held in regs)
    bf16x8 qf[2][2];
#pragma unroll
    for (int m = 0; m < 2; ++m) {
        qf[m][0] = *(const bf16x8*)&Qp[(m * 16 + lr) * 64 + 8 * lg];
        qf[m][1] = *(const bf16x8*)&Qp[(m * 16 + lr) * 64 + 32 + 8 * lg];
    }

    bf16x8 ones;
#pragma unroll
    for (int e = 0; e < 8; ++e) ones[e] = (short)0x3F80;   // bf16 1.0

    f32x4 acc[2][4];
#pragma unroll
    for (int m = 0; m < 2; ++m)
#pragma unroll
        for (int d0 = 0; d0 < 4; ++d0) acc[m][d0] = zero4;
    f32x4 lacc[2] = {zero4, zero4};

    char* const Pb = (char*)&Pl[wv][0];
    const int psw = lr & 7;   // P chunk swizzle key

    for (int kt = 0; kt < 32; ++kt) {
        const int kbase = kt * 64;

        // S^T = mfma(K, Q) per 16-kv tile; K fragments straight from global (L2)
#pragma unroll
        for (int n = 0; n < 4; ++n) {
            const char* kr = Kp + (size_t)(kbase + n * 16 + lr) * 128 + 16 * lg;
            const bf16x8 k0 = *(const bf16x8*)kr;
            const bf16x8 k1 = *(const bf16x8*)(kr + 64);
#pragma unroll
            for (int m = 0; m < 2; ++m) {
                f32x4 st = MFMA_BF16(k0, qf[m][0], zero4);
                st = MFMA_BF16(k1, qf[m][1], st);
                const float p0 = __builtin_amdgcn_exp2f(st[0]);
                const float p1 = __builtin_amdgcn_exp2f(st[1]);
                const float p2 = __builtin_amdgcn_exp2f(st[2]);
                const float p3 = __builtin_amdgcn_exp2f(st[3]);
                u32x2 pw;
                pw.x = cvt_pk_bf16(p0, p1);
                pw.y = cvt_pk_bf16(p2, p3);
                // P[q=m16+lr][kv=n16+4lg+{0..3}] -> chunk 2n+(lg>>1), byte 8*(lg&1)
                *(u32x2*)(Pb + (m * 16 + lr) * 128 +
                          (((2 * n + (lg >> 1)) ^ psw) << 4) + ((lg & 1) << 3)) = pw;
            }
        }

        // read P as PV A-fragments: lane (lr,lg) gets P[q=m16+lr][kv=hf*32+8lg+{0..7}]
        bf16x8 pf[2][2];
#pragma unroll
        for (int m = 0; m < 2; ++m) {
#pragma unroll
            for (int hf = 0; hf < 2; ++hf) {
                pf[m][hf] = *(const bf16x8*)(Pb + (m * 16 + lr) * 128 +
                                             (((hf * 4 + lg) ^ psw) << 4));
                lacc[m] = MFMA_BF16(pf[m][hf], ones, lacc[m]);   // row-sum of P
            }
        }

        // acc += P V ; V fragments straight from global (L2)
#pragma unroll
        for (int hf = 0; hf < 2; ++hf) {
#pragma unroll
            for (int d0 = 0; d0 < 4; ++d0) {
                const bf16x8 vf = *(const bf16x8*)(Vp + (size_t)(d0 * 16 + lr) * 4096 +
                                                   (kbase + hf * 32 + 8 * lg) * 2);
#pragma unroll
                for (int m = 0; m < 2; ++m)
                    acc[m][d0] = MFMA_BF16(pf[m][hf], vf, acc[m][d0]);
            }
        }
    }

#pragma unroll
    for (int m = 0; m < 2; ++m) {
#pragma unroll
        for (int d0 = 0; d0 < 4; ++d0) {
#pragma unroll
            for (int r = 0; r < 4; ++r) {
                const int row = q0 + m * 16 + lg * 4 + r;
                const int col = (h << 6) + d0 * 16 + lr;
                AO[(((size_t)b * 2048 + row) << 10) + col] = f2bf(acc[m][d0][r] / lacc[m][r]);
            }
        }
    }
}

extern "C" void kernel_launch(void* const* d_in, const int* in_sizes, int n_in,
                              void* d_out, int out_size, void* d_ws, size_t ws_size,
                              hipStream_t stream) {
    const float* q   = (const float*)d_in[0];
    const float* k   = (const float*)d_in[1];
    const float* v   = (const float*)d_in[2];
    const float* w_q = (const float*)d_in[3];
    const float* b_q = (const float*)d_in[4];
    const float* w_k = (const float*)d_in[5];
    const float* b_k = (const float*)d_in[6];
    const float* w_v = (const float*)d_in[7];
    const float* b_v = (const float*)d_in[8];
    const float* w_o = (const float*)d_in[9];
    const float* b_o = (const float*)d_in[10];
    float* out = (float*)d_out;

    char* ws = (char*)d_ws;
    unsigned short* qb  = (unsigned short*)(ws + 0);          // 8 MB  [4096][1024] bf16
    unsigned short* kb  = (unsigned short*)(ws + 8388608);    // 8 MB
    unsigned short* vb  = (unsigned short*)(ws + 16777216);   // 8 MB
    unsigned short* wtq = (unsigned short*)(ws + 25165824);   // 2 MB  [N][K] bf16
    unsigned short* wtk = (unsigned short*)(ws + 27262976);
    unsigned short* wtv = (unsigned short*)(ws + 29360128);
    unsigned short* wto = (unsigned short*)(ws + 31457280);
    unsigned short* Qh  = (unsigned short*)(ws + 33554432);   // 8 MB  [2][16][2048][64]
    unsigned short* Kh  = (unsigned short*)(ws + 41943040);   // 8 MB
    unsigned short* Vt  = (unsigned short*)(ws + 50331648);   // 8 MB  [2][16][64][2048]
    unsigned short* AO  = (unsigned short*)(ws + 58720256);   // 8 MB  [4096][1024]

    const int n4 = (4096 * 1024) / 4;
    cvt3_kernel<<<dim3(4096, 3), 256, 0, stream>>>(q, k, v, qb, kb, vb, n4);

    wtrans4_kernel<<<dim3(32, 32, 4), dim3(32, 8), 0, stream>>>(
        w_q, w_k, w_v, w_o, wtq, wtk, wtv, wto);

    gemm_qkv_kernel<<<dim3(32, 16, 3), 256, 0, stream>>>(
        qb, kb, vb, wtq, wtk, wtv, b_q, b_k, b_v, Qh, Kh, Vt);

    attn_kernel<<<dim3(512), 256, 0, stream>>>(Qh, Kh, Vt, AO);

    gemm_o_kernel<<<dim3(32, 16), 256, 0, stream>>>(AO, wto, b_o, out);
}

// Round 10
// 148.956 us; speedup vs baseline: 1.3854x; 1.3854x over previous
//
#include <hip/hip_runtime.h>
#include <hip/hip_bf16.h>
#include <stdint.h>

typedef short bf16x8 __attribute__((ext_vector_type(8)));
typedef float f32x4 __attribute__((ext_vector_type(4)));
typedef unsigned u32x2 __attribute__((ext_vector_type(2)));

#define MFMA_BF16(a, b, c) __builtin_amdgcn_mfma_f32_16x16x32_bf16((a), (b), (c), 0, 0, 0)

#define GLOAD_LDS16(g, l) __builtin_amdgcn_global_load_lds( \
    (const __attribute__((address_space(1))) void*)(g),     \
    (__attribute__((address_space(3))) void*)(l), 16, 0, 0)

__device__ __forceinline__ unsigned short f2bf(float f) {
    union { float f; unsigned u; } v; v.f = f;
    unsigned r = v.u + 0x7FFFu + ((v.u >> 16) & 1u);  // RNE
    return (unsigned short)(r >> 16);
}

__device__ __forceinline__ unsigned cvt_pk_bf16(float a, float b) {
    unsigned r;
    asm("v_cvt_pk_bf16_f32 %0, %1, %2" : "=v"(r) : "v"(a), "v"(b));
    return r;  // low16 = bf16(a), high16 = bf16(b), RNE
}

// ---------------- fp32 -> bf16 convert, 3 tensors in one launch ----------------
__global__ void cvt3_kernel(const float* __restrict__ i0, const float* __restrict__ i1,
                            const float* __restrict__ i2,
                            unsigned short* __restrict__ o0, unsigned short* __restrict__ o1,
                            unsigned short* __restrict__ o2, int n4) {
    const int z = blockIdx.y;
    const float* in = z == 0 ? i0 : (z == 1 ? i1 : i2);
    unsigned short* out = z == 0 ? o0 : (z == 1 ? o1 : o2);
    int i = blockIdx.x * blockDim.x + threadIdx.x;
    if (i >= n4) return;
    float4 v = ((const float4*)in)[i];
    ushort4 o;
    o.x = f2bf(v.x); o.y = f2bf(v.y); o.z = f2bf(v.z); o.w = f2bf(v.w);
    ((ushort4*)out)[i] = o;
}

// ---------------- weight transpose + convert, 4 weights in one launch ----------------
__global__ void wtrans4_kernel(const float* __restrict__ w0, const float* __restrict__ w1,
                               const float* __restrict__ w2, const float* __restrict__ w3,
                               unsigned short* __restrict__ t0, unsigned short* __restrict__ t1,
                               unsigned short* __restrict__ t2, unsigned short* __restrict__ t3) {
    __shared__ float tile[32][33];
    const int z = blockIdx.z;
    const float* w = z == 0 ? w0 : (z == 1 ? w1 : (z == 2 ? w2 : w3));
    unsigned short* wt = z == 0 ? t0 : (z == 1 ? t1 : (z == 2 ? t2 : t3));
    const int tx = threadIdx.x, ty = threadIdx.y;
    const int bx = blockIdx.x, by = blockIdx.y;
#pragma unroll
    for (int i = 0; i < 4; ++i)
        tile[ty + 8 * i][tx] = w[(size_t)(by * 32 + ty + 8 * i) * 1024 + bx * 32 + tx];
    __syncthreads();
#pragma unroll
    for (int i = 0; i < 4; ++i)
        wt[(size_t)(bx * 32 + ty + 8 * i) * 1024 + by * 32 + tx] = f2bf(tile[tx][ty + 8 * i]);
}

// ---------------- fused QKV GEMM, BM=128 BN=64: z=0 Q (scaled by log2e/8), z=1 K, z=2 V (transposed) ----------------
__global__ __launch_bounds__(256) void gemm_qkv_kernel(
    const unsigned short* __restrict__ A0, const unsigned short* __restrict__ A1,
    const unsigned short* __restrict__ A2,
    const unsigned short* __restrict__ W0, const unsigned short* __restrict__ W1,
    const unsigned short* __restrict__ W2,
    const float* __restrict__ c0, const float* __restrict__ c1, const float* __restrict__ c2,
    unsigned short* __restrict__ O0, unsigned short* __restrict__ O1,
    unsigned short* __restrict__ O2)
{
    const int z = blockIdx.z;
    const unsigned short* A  = z == 0 ? A0 : (z == 1 ? A1 : A2);
    const unsigned short* Bt = z == 0 ? W0 : (z == 1 ? W1 : W2);
    const float* bias        = z == 0 ? c0 : (z == 1 ? c1 : c2);
    unsigned short* out      = z == 0 ? O0 : (z == 1 ? O1 : O2);
    const float qscale       = z == 0 ? 0.18033688f : 1.0f;   // log2(e)/8

    __shared__ unsigned short As[128 * 64];
    __shared__ unsigned short Bs[64 * 64];
    const int t = threadIdx.x;
    const int lane = t & 63, w = t >> 6;
    const int wr = w >> 1, wc = w & 1;
    const int lr = lane & 15, lg = lane >> 4;
    const int m0 = blockIdx.x * 128, n0 = blockIdx.y * 64;

    f32x4 acc[4][2];
#pragma unroll
    for (int m = 0; m < 4; ++m)
#pragma unroll
        for (int n = 0; n < 2; ++n)
            acc[m][n] = (f32x4){0.f, 0.f, 0.f, 0.f};

    for (int k0 = 0; k0 < 1024; k0 += 64) {
        __syncthreads();
#pragma unroll
        for (int r = 0; r < 4; ++r) {
            int off = r * 4096 + t * 16;
            int row = off >> 7, cb = off & 127;
            GLOAD_LDS16((const char*)A + ((size_t)(m0 + row) * 1024 + k0) * 2 + cb, (char*)As + off);
        }
#pragma unroll
        for (int r = 0; r < 2; ++r) {
            int off = r * 4096 + t * 16;
            int row = off >> 7, cb = off & 127;
            GLOAD_LDS16((const char*)Bt + ((size_t)(n0 + row) * 1024 + k0) * 2 + cb, (char*)Bs + off);
        }
        __syncthreads();
#pragma unroll
        for (int kk = 0; kk < 2; ++kk) {
            bf16x8 af[4], bfr[2];
#pragma unroll
            for (int m = 0; m < 4; ++m)
                af[m] = *(const bf16x8*)&As[(wr * 64 + m * 16 + lr) * 64 + kk * 32 + 8 * lg];
#pragma unroll
            for (int n = 0; n < 2; ++n)
                bfr[n] = *(const bf16x8*)&Bs[(wc * 32 + n * 16 + lr) * 64 + kk * 32 + 8 * lg];
#pragma unroll
            for (int m = 0; m < 4; ++m)
#pragma unroll
                for (int n = 0; n < 2; ++n)
                    acc[m][n] = MFMA_BF16(af[m], bfr[n], acc[m][n]);
        }
    }

#pragma unroll
    for (int m = 0; m < 4; ++m) {
#pragma unroll
        for (int n = 0; n < 2; ++n) {
            const int gn = n0 + wc * 32 + n * 16 + lr;
            const float bv = bias[gn];
#pragma unroll
            for (int r = 0; r < 4; ++r) {
                const int gm = m0 + wr * 64 + m * 16 + lg * 4 + r;
                const float vv = (acc[m][n][r] + bv) * qscale;
                int bi = gm >> 11, pos = gm & 2047, hh = gn >> 6, dh = gn & 63;
                if (z != 2)
                    out[(((size_t)(bi * 16 + hh) * 2048 + pos) << 6) + dh] = f2bf(vv);
                else
                    out[(((size_t)(bi * 16 + hh) * 64 + dh) << 11) + pos] = f2bf(vv);
            }
        }
    }
}

// ---------------- output-projection GEMM, BM=128 BN=64: fp32 out [4096][1024] ----------------
__global__ __launch_bounds__(256) void gemm_o_kernel(
    const unsigned short* __restrict__ A,
    const unsigned short* __restrict__ Bt,
    const float* __restrict__ bias,
    float* __restrict__ out)
{
    __shared__ unsigned short As[128 * 64];
    __shared__ unsigned short Bs[64 * 64];
    const int t = threadIdx.x;
    const int lane = t & 63, w = t >> 6;
    const int wr = w >> 1, wc = w & 1;
    const int lr = lane & 15, lg = lane >> 4;
    const int m0 = blockIdx.x * 128, n0 = blockIdx.y * 64;

    f32x4 acc[4][2];
#pragma unroll
    for (int m = 0; m < 4; ++m)
#pragma unroll
        for (int n = 0; n < 2; ++n)
            acc[m][n] = (f32x4){0.f, 0.f, 0.f, 0.f};

    for (int k0 = 0; k0 < 1024; k0 += 64) {
        __syncthreads();
#pragma unroll
        for (int r = 0; r < 4; ++r) {
            int off = r * 4096 + t * 16;
            int row = off >> 7, cb = off & 127;
            GLOAD_LDS16((const char*)A + ((size_t)(m0 + row) * 1024 + k0) * 2 + cb, (char*)As + off);
        }
#pragma unroll
        for (int r = 0; r < 2; ++r) {
            int off = r * 4096 + t * 16;
            int row = off >> 7, cb = off & 127;
            GLOAD_LDS16((const char*)Bt + ((size_t)(n0 + row) * 1024 + k0) * 2 + cb, (char*)Bs + off);
        }
        __syncthreads();
#pragma unroll
        for (int kk = 0; kk < 2; ++kk) {
            bf16x8 af[4], bfr[2];
#pragma unroll
            for (int m = 0; m < 4; ++m)
                af[m] = *(const bf16x8*)&As[(wr * 64 + m * 16 + lr) * 64 + kk * 32 + 8 * lg];
#pragma unroll
            for (int n = 0; n < 2; ++n)
                bfr[n] = *(const bf16x8*)&Bs[(wc * 32 + n * 16 + lr) * 64 + kk * 32 + 8 * lg];
#pragma unroll
            for (int m = 0; m < 4; ++m)
#pragma unroll
                for (int n = 0; n < 2; ++n)
                    acc[m][n] = MFMA_BF16(af[m], bfr[n], acc[m][n]);
        }
    }

#pragma unroll
    for (int m = 0; m < 4; ++m)
#pragma unroll
        for (int n = 0; n < 2; ++n) {
            const int gn = n0 + wc * 32 + n * 16 + lr;
            const float bv = bias[gn];
#pragma unroll
            for (int r = 0; r < 4; ++r) {
                const int gm = m0 + wr * 64 + m * 16 + lg * 4 + r;
                out[((size_t)gm << 10) + gn] = acc[m][n][r] + bv;
            }
        }
}

// ---------------- flash attention v4 (round-6 proven) + setprio on PV MFMAs ----------------
// Qh bf16 [B][H][L][64] (pre-scaled by log2e/8); Kh bf16 [B][H][L][64]; Vt bf16 [B][H][64][L]
// AO bf16 [B][L][1024]. grid (L/128, H, B), block 256 (4 waves x 32 q-rows). KVBLK=64, K/V dbuf.
__global__ __launch_bounds__(256) void attn_kernel(
    const unsigned short* __restrict__ Qh,
    const unsigned short* __restrict__ Kh,
    const unsigned short* __restrict__ Vt,
    unsigned short* __restrict__ AO)
{
    __shared__ unsigned short Ks[2][4096];   // [64 kv][64 d], row-XOR-swizzled
    __shared__ unsigned short Vs[2][4096];   // [64 d][64 kv], row-XOR-swizzled
    __shared__ unsigned short Pl[4][2048];   // per-wave [32 q][64 kv], chunk-XOR-swizzled

    const int t = threadIdx.x;
    const int lane = t & 63, wv = t >> 6;    // 4 waves
    const int lr = lane & 15, lg = lane >> 4;
    const int qb = blockIdx.x, h = blockIdx.y, b = blockIdx.z;
    const int q0 = qb * 128 + wv * 32;

    const char* Kp = (const char*)(Kh + (((size_t)(b * 16 + h) * 2048) << 6));
    const char* Vp = (const char*)(Vt + (((size_t)(b * 16 + h) * 64) << 11));
    const unsigned short* Qp = Qh + (((size_t)(b * 16 + h) * 2048 + q0) << 6);

    const f32x4 zero4 = {0.f, 0.f, 0.f, 0.f};

    bf16x8 qf[2][2];
#pragma unroll
    for (int m = 0; m < 2; ++m) {
        qf[m][0] = *(const bf16x8*)&Qp[(m * 16 + lr) * 64 + 8 * lg];
        qf[m][1] = *(const bf16x8*)&Qp[(m * 16 + lr) * 64 + 32 + 8 * lg];
    }

    bf16x8 ones;
#pragma unroll
    for (int e = 0; e < 8; ++e) ones[e] = (short)0x3F80;   // bf16 1.0

    f32x4 acc[2][4];
#pragma unroll
    for (int m = 0; m < 2; ++m)
#pragma unroll
        for (int d0 = 0; d0 < 4; ++d0) acc[m][d0] = zero4;
    f32x4 lacc[2] = {zero4, zero4};

    auto stage = [&](int sbuf, int kt) {
        const size_t kb = (size_t)kt << 6;
#pragma unroll
        for (int i = 0; i < 2; ++i) {
            const int off = i * 4096 + t * 16;
            const int row = off >> 7, cb = off & 127;
            const int scb = cb ^ ((row & 7) << 4);
            GLOAD_LDS16(Kp + ((kb + row) << 7) + scb, (char*)&Ks[sbuf][0] + off);
        }
#pragma unroll
        for (int i = 0; i < 2; ++i) {
            const int off = i * 4096 + t * 16;
            const int row = off >> 7, cb = off & 127;
            const int scb = cb ^ ((row & 7) << 4);
            GLOAD_LDS16(Vp + (size_t)row * 4096 + (kb << 1) + scb, (char*)&Vs[sbuf][0] + off);
        }
    };

    stage(0, 0);
    __syncthreads();
    int buf = 0;
    char* const Pb = (char*)&Pl[wv][0];
    const int psw = lr & 7;   // P chunk swizzle key

    for (int kt = 0; kt < 32; ++kt) {
        if (kt + 1 < 32) stage(buf ^ 1, kt + 1);

        const char* Kb = (const char*)&Ks[buf][0];
        const char* Vb = (const char*)&Vs[buf][0];

        // S^T = mfma(K, Q) per 16-kv tile; exp2 + pack + b64 store into P
#pragma unroll
        for (int n = 0; n < 4; ++n) {
            const int row = n * 16 + lr;
            const int sw = (row & 7) << 4;
            const bf16x8 k0 = *(const bf16x8*)(Kb + row * 128 + ((lg * 16) ^ sw));
            const bf16x8 k1 = *(const bf16x8*)(Kb + row * 128 + ((64 + lg * 16) ^ sw));
#pragma unroll
            for (int m = 0; m < 2; ++m) {
                f32x4 st = MFMA_BF16(k0, qf[m][0], zero4);
                st = MFMA_BF16(k1, qf[m][1], st);
                const float p0 = __builtin_amdgcn_exp2f(st[0]);
                const float p1 = __builtin_amdgcn_exp2f(st[1]);
                const float p2 = __builtin_amdgcn_exp2f(st[2]);
                const float p3 = __builtin_amdgcn_exp2f(st[3]);
                u32x2 pw;
                pw.x = cvt_pk_bf16(p0, p1);
                pw.y = cvt_pk_bf16(p2, p3);
                // P[q=m16+lr][kv=n16+4lg+{0..3}] -> chunk 2n+(lg>>1), byte-in-chunk 8*(lg&1)
                *(u32x2*)(Pb + (m * 16 + lr) * 128 +
                          (((2 * n + (lg >> 1)) ^ psw) << 4) + ((lg & 1) << 3)) = pw;
            }
        }

        // read P as PV A-fragments: lane (lr,lg) gets P[q=m16+lr][kv=hf*32+8lg+{0..7}]
        bf16x8 pf[2][2];
#pragma unroll
        for (int m = 0; m < 2; ++m) {
#pragma unroll
            for (int hf = 0; hf < 2; ++hf) {
                pf[m][hf] = *(const bf16x8*)(Pb + (m * 16 + lr) * 128 +
                                             (((hf * 4 + lg) ^ psw) << 4));
                lacc[m] = MFMA_BF16(pf[m][hf], ones, lacc[m]);   // row-sum of P
            }
        }

        // acc += P V  (setprio: favor MFMA-issuing wave — T5, correctness-neutral)
        __builtin_amdgcn_s_setprio(1);
#pragma unroll
        for (int hf = 0; hf < 2; ++hf) {
#pragma unroll
            for (int d0 = 0; d0 < 4; ++d0) {
                const int vrow = d0 * 16 + lr;
                const int sw = (vrow & 7) << 4;
                const bf16x8 vf = *(const bf16x8*)(Vb + vrow * 128 + ((hf * 64 + lg * 16) ^ sw));
#pragma unroll
                for (int m = 0; m < 2; ++m)
                    acc[m][d0] = MFMA_BF16(pf[m][hf], vf, acc[m][d0]);
            }
        }
        __builtin_amdgcn_s_setprio(0);

        __syncthreads();
        buf ^= 1;
    }

#pragma unroll
    for (int m = 0; m < 2; ++m) {
#pragma unroll
        for (int d0 = 0; d0 < 4; ++d0) {
#pragma unroll
            for (int r = 0; r < 4; ++r) {
                const int row = q0 + m * 16 + lg * 4 + r;
                const int col = (h << 6) + d0 * 16 + lr;
                AO[(((size_t)b * 2048 + row) << 10) + col] = f2bf(acc[m][d0][r] / lacc[m][r]);
            }
        }
    }
}

extern "C" void kernel_launch(void* const* d_in, const int* in_sizes, int n_in,
                              void* d_out, int out_size, void* d_ws, size_t ws_size,
                              hipStream_t stream) {
    const float* q   = (const float*)d_in[0];
    const float* k   = (const float*)d_in[1];
    const float* v   = (const float*)d_in[2];
    const float* w_q = (const float*)d_in[3];
    const float* b_q = (const float*)d_in[4];
    const float* w_k = (const float*)d_in[5];
    const float* b_k = (const float*)d_in[6];
    const float* w_v = (const float*)d_in[7];
    const float* b_v = (const float*)d_in[8];
    const float* w_o = (const float*)d_in[9];
    const float* b_o = (const float*)d_in[10];
    float* out = (float*)d_out;

    char* ws = (char*)d_ws;
    unsigned short* qb  = (unsigned short*)(ws + 0);          // 8 MB  [4096][1024] bf16
    unsigned short* kb  = (unsigned short*)(ws + 8388608);    // 8 MB
    unsigned short* vb  = (unsigned short*)(ws + 16777216);   // 8 MB
    unsigned short* wtq = (unsigned short*)(ws + 25165824);   // 2 MB  [N][K] bf16
    unsigned short* wtk = (unsigned short*)(ws + 27262976);
    unsigned short* wtv = (unsigned short*)(ws + 29360128);
    unsigned short* wto = (unsigned short*)(ws + 31457280);
    unsigned short* Qh  = (unsigned short*)(ws + 33554432);   // 8 MB  [2][16][2048][64]
    unsigned short* Kh  = (unsigned short*)(ws + 41943040);   // 8 MB
    unsigned short* Vt  = (unsigned short*)(ws + 50331648);   // 8 MB  [2][16][64][2048]
    unsigned short* AO  = (unsigned short*)(ws + 58720256);   // 8 MB  [4096][1024]

    const int n4 = (4096 * 1024) / 4;
    cvt3_kernel<<<dim3(4096, 3), 256, 0, stream>>>(q, k, v, qb, kb, vb, n4);

    wtrans4_kernel<<<dim3(32, 32, 4), dim3(32, 8), 0, stream>>>(
        w_q, w_k, w_v, w_o, wtq, wtk, wtv, wto);

    gemm_qkv_kernel<<<dim3(32, 16, 3), 256, 0, stream>>>(
        qb, kb, vb, wtq, wtk, wtv, b_q, b_k, b_v, Qh, Kh, Vt);

    attn_kernel<<<dim3(16, 16, 2), 256, 0, stream>>>(Qh, Kh, Vt, AO);

    gemm_o_kernel<<<dim3(32, 16), 256, 0, stream>>>(AO, wto, b_o, out);
}

// Round 12
// 134.882 us; speedup vs baseline: 1.5300x; 1.1043x over previous
//
#include <hip/hip_runtime.h>
#include <hip/hip_bf16.h>
#include <stdint.h>

typedef short bf16x8 __attribute__((ext_vector_type(8)));
typedef float f32x4 __attribute__((ext_vector_type(4)));
typedef unsigned u32x2 __attribute__((ext_vector_type(2)));

#define MFMA_BF16(a, b, c) __builtin_amdgcn_mfma_f32_16x16x32_bf16((a), (b), (c), 0, 0, 0)

#define GLOAD_LDS16(g, l) __builtin_amdgcn_global_load_lds( \
    (const __attribute__((address_space(1))) void*)(g),     \
    (__attribute__((address_space(3))) void*)(l), 16, 0, 0)

__device__ __forceinline__ unsigned short f2bf(float f) {
    union { float f; unsigned u; } v; v.f = f;
    unsigned r = v.u + 0x7FFFu + ((v.u >> 16) & 1u);  // RNE
    return (unsigned short)(r >> 16);
}

__device__ __forceinline__ unsigned cvt_pk_bf16(float a, float b) {
    unsigned r;
    asm("v_cvt_pk_bf16_f32 %0, %1, %2" : "=v"(r) : "v"(a), "v"(b));
    return r;  // low16 = bf16(a), high16 = bf16(b), RNE
}

// ---------------- fp32 -> bf16 convert, 3 tensors in one launch ----------------
__global__ void cvt3_kernel(const float* __restrict__ i0, const float* __restrict__ i1,
                            const float* __restrict__ i2,
                            unsigned short* __restrict__ o0, unsigned short* __restrict__ o1,
                            unsigned short* __restrict__ o2, int n4) {
    const int z = blockIdx.y;
    const float* in = z == 0 ? i0 : (z == 1 ? i1 : i2);
    unsigned short* out = z == 0 ? o0 : (z == 1 ? o1 : o2);
    int i = blockIdx.x * blockDim.x + threadIdx.x;
    if (i >= n4) return;
    float4 v = ((const float4*)in)[i];
    ushort4 o;
    o.x = f2bf(v.x); o.y = f2bf(v.y); o.z = f2bf(v.z); o.w = f2bf(v.w);
    ((ushort4*)out)[i] = o;
}

// ---------------- weight transpose + convert, 4 weights in one launch ----------------
__global__ void wtrans4_kernel(const float* __restrict__ w0, const float* __restrict__ w1,
                               const float* __restrict__ w2, const float* __restrict__ w3,
                               unsigned short* __restrict__ t0, unsigned short* __restrict__ t1,
                               unsigned short* __restrict__ t2, unsigned short* __restrict__ t3) {
    __shared__ float tile[32][33];
    const int z = blockIdx.z;
    const float* w = z == 0 ? w0 : (z == 1 ? w1 : (z == 2 ? w2 : w3));
    unsigned short* wt = z == 0 ? t0 : (z == 1 ? t1 : (z == 2 ? t2 : t3));
    const int tx = threadIdx.x, ty = threadIdx.y;
    const int bx = blockIdx.x, by = blockIdx.y;
#pragma unroll
    for (int i = 0; i < 4; ++i)
        tile[ty + 8 * i][tx] = w[(size_t)(by * 32 + ty + 8 * i) * 1024 + bx * 32 + tx];
    __syncthreads();
#pragma unroll
    for (int i = 0; i < 4; ++i)
        wt[(size_t)(bx * 32 + ty + 8 * i) * 1024 + by * 32 + tx] = f2bf(tile[tx][ty + 8 * i]);
}

// ---------------- fused QKV GEMM, BM=128 BN=64, T2-swizzled LDS ----------------
// z=0 Q (scaled by log2e/8), z=1 K, z=2 V (transposed head layout)
__global__ __launch_bounds__(256) void gemm_qkv_kernel(
    const unsigned short* __restrict__ A0, const unsigned short* __restrict__ A1,
    const unsigned short* __restrict__ A2,
    const unsigned short* __restrict__ W0, const unsigned short* __restrict__ W1,
    const unsigned short* __restrict__ W2,
    const float* __restrict__ c0, const float* __restrict__ c1, const float* __restrict__ c2,
    unsigned short* __restrict__ O0, unsigned short* __restrict__ O1,
    unsigned short* __restrict__ O2)
{
    const int z = blockIdx.z;
    const unsigned short* A  = z == 0 ? A0 : (z == 1 ? A1 : A2);
    const unsigned short* Bt = z == 0 ? W0 : (z == 1 ? W1 : W2);
    const float* bias        = z == 0 ? c0 : (z == 1 ? c1 : c2);
    unsigned short* out      = z == 0 ? O0 : (z == 1 ? O1 : O2);
    const float qscale       = z == 0 ? 0.18033688f : 1.0f;   // log2(e)/8

    __shared__ unsigned short As[128 * 64];
    __shared__ unsigned short Bs[64 * 64];
    const int t = threadIdx.x;
    const int lane = t & 63, w = t >> 6;
    const int wr = w >> 1, wc = w & 1;
    const int lr = lane & 15, lg = lane >> 4;
    const int m0 = blockIdx.x * 128, n0 = blockIdx.y * 64;
    const int fsw = (lr & 7) << 4;   // fragment-read swizzle key (row&7 == lr&7)

    f32x4 acc[4][2];
#pragma unroll
    for (int m = 0; m < 4; ++m)
#pragma unroll
        for (int n = 0; n < 2; ++n)
            acc[m][n] = (f32x4){0.f, 0.f, 0.f, 0.f};

    for (int k0 = 0; k0 < 1024; k0 += 64) {
        __syncthreads();
#pragma unroll
        for (int r = 0; r < 4; ++r) {
            int off = r * 4096 + t * 16;
            int row = off >> 7, cb = off & 127;
            int scb = cb ^ ((row & 7) << 4);   // pre-swizzled source, linear LDS dest
            GLOAD_LDS16((const char*)A + ((size_t)(m0 + row) * 1024 + k0) * 2 + scb, (char*)As + off);
        }
#pragma unroll
        for (int r = 0; r < 2; ++r) {
            int off = r * 4096 + t * 16;
            int row = off >> 7, cb = off & 127;
            int scb = cb ^ ((row & 7) << 4);
            GLOAD_LDS16((const char*)Bt + ((size_t)(n0 + row) * 1024 + k0) * 2 + scb, (char*)Bs + off);
        }
        __syncthreads();
#pragma unroll
        for (int kk = 0; kk < 2; ++kk) {
            bf16x8 af[4], bfr[2];
#pragma unroll
            for (int m = 0; m < 4; ++m) {
                const int row = wr * 64 + m * 16 + lr;
                af[m] = *(const bf16x8*)((const char*)As + row * 128 +
                                         ((kk * 64 + lg * 16) ^ fsw));
            }
#pragma unroll
            for (int n = 0; n < 2; ++n) {
                const int row = wc * 32 + n * 16 + lr;
                bfr[n] = *(const bf16x8*)((const char*)Bs + row * 128 +
                                          ((kk * 64 + lg * 16) ^ fsw));
            }
#pragma unroll
            for (int m = 0; m < 4; ++m)
#pragma unroll
                for (int n = 0; n < 2; ++n)
                    acc[m][n] = MFMA_BF16(af[m], bfr[n], acc[m][n]);
        }
    }

#pragma unroll
    for (int m = 0; m < 4; ++m) {
#pragma unroll
        for (int n = 0; n < 2; ++n) {
            const int gn = n0 + wc * 32 + n * 16 + lr;
            const float bv = bias[gn];
#pragma unroll
            for (int r = 0; r < 4; ++r) {
                const int gm = m0 + wr * 64 + m * 16 + lg * 4 + r;
                const float vv = (acc[m][n][r] + bv) * qscale;
                int bi = gm >> 11, pos = gm & 2047, hh = gn >> 6, dh = gn & 63;
                if (z != 2)
                    out[(((size_t)(bi * 16 + hh) * 2048 + pos) << 6) + dh] = f2bf(vv);
                else
                    out[(((size_t)(bi * 16 + hh) * 64 + dh) << 11) + pos] = f2bf(vv);
            }
        }
    }
}

// ---------------- output-projection GEMM, BM=128 BN=64, T2-swizzled LDS: fp32 out ----------------
__global__ __launch_bounds__(256) void gemm_o_kernel(
    const unsigned short* __restrict__ A,
    const unsigned short* __restrict__ Bt,
    const float* __restrict__ bias,
    float* __restrict__ out)
{
    __shared__ unsigned short As[128 * 64];
    __shared__ unsigned short Bs[64 * 64];
    const int t = threadIdx.x;
    const int lane = t & 63, w = t >> 6;
    const int wr = w >> 1, wc = w & 1;
    const int lr = lane & 15, lg = lane >> 4;
    const int m0 = blockIdx.x * 128, n0 = blockIdx.y * 64;
    const int fsw = (lr & 7) << 4;

    f32x4 acc[4][2];
#pragma unroll
    for (int m = 0; m < 4; ++m)
#pragma unroll
        for (int n = 0; n < 2; ++n)
            acc[m][n] = (f32x4){0.f, 0.f, 0.f, 0.f};

    for (int k0 = 0; k0 < 1024; k0 += 64) {
        __syncthreads();
#pragma unroll
        for (int r = 0; r < 4; ++r) {
            int off = r * 4096 + t * 16;
            int row = off >> 7, cb = off & 127;
            int scb = cb ^ ((row & 7) << 4);
            GLOAD_LDS16((const char*)A + ((size_t)(m0 + row) * 1024 + k0) * 2 + scb, (char*)As + off);
        }
#pragma unroll
        for (int r = 0; r < 2; ++r) {
            int off = r * 4096 + t * 16;
            int row = off >> 7, cb = off & 127;
            int scb = cb ^ ((row & 7) << 4);
            GLOAD_LDS16((const char*)Bt + ((size_t)(n0 + row) * 1024 + k0) * 2 + scb, (char*)Bs + off);
        }
        __syncthreads();
#pragma unroll
        for (int kk = 0; kk < 2; ++kk) {
            bf16x8 af[4], bfr[2];
#pragma unroll
            for (int m = 0; m < 4; ++m) {
                const int row = wr * 64 + m * 16 + lr;
                af[m] = *(const bf16x8*)((const char*)As + row * 128 +
                                         ((kk * 64 + lg * 16) ^ fsw));
            }
#pragma unroll
            for (int n = 0; n < 2; ++n) {
                const int row = wc * 32 + n * 16 + lr;
                bfr[n] = *(const bf16x8*)((const char*)Bs + row * 128 +
                                          ((kk * 64 + lg * 16) ^ fsw));
            }
#pragma unroll
            for (int m = 0; m < 4; ++m)
#pragma unroll
                for (int n = 0; n < 2; ++n)
                    acc[m][n] = MFMA_BF16(af[m], bfr[n], acc[m][n]);
        }
    }

#pragma unroll
    for (int m = 0; m < 4; ++m)
#pragma unroll
        for (int n = 0; n < 2; ++n) {
            const int gn = n0 + wc * 32 + n * 16 + lr;
            const float bv = bias[gn];
#pragma unroll
            for (int r = 0; r < 4; ++r) {
                const int gm = m0 + wr * 64 + m * 16 + lg * 4 + r;
                out[((size_t)gm << 10) + gn] = acc[m][n][r] + bv;
            }
        }
}

// ---------------- flash attention v4 (round-10 proven, 66.5us) — UNCHANGED ----------------
__global__ __launch_bounds__(256) void attn_kernel(
    const unsigned short* __restrict__ Qh,
    const unsigned short* __restrict__ Kh,
    const unsigned short* __restrict__ Vt,
    unsigned short* __restrict__ AO)
{
    __shared__ unsigned short Ks[2][4096];   // [64 kv][64 d], row-XOR-swizzled
    __shared__ unsigned short Vs[2][4096];   // [64 d][64 kv], row-XOR-swizzled
    __shared__ unsigned short Pl[4][2048];   // per-wave [32 q][64 kv], chunk-XOR-swizzled

    const int t = threadIdx.x;
    const int lane = t & 63, wv = t >> 6;    // 4 waves
    const int lr = lane & 15, lg = lane >> 4;
    const int qb = blockIdx.x, h = blockIdx.y, b = blockIdx.z;
    const int q0 = qb * 128 + wv * 32;

    const char* Kp = (const char*)(Kh + (((size_t)(b * 16 + h) * 2048) << 6));
    const char* Vp = (const char*)(Vt + (((size_t)(b * 16 + h) * 64) << 11));
    const unsigned short* Qp = Qh + (((size_t)(b * 16 + h) * 2048 + q0) << 6);

    const f32x4 zero4 = {0.f, 0.f, 0.f, 0.f};

    bf16x8 qf[2][2];
#pragma unroll
    for (int m = 0; m < 2; ++m) {
        qf[m][0] = *(const bf16x8*)&Qp[(m * 16 + lr) * 64 + 8 * lg];
        qf[m][1] = *(const bf16x8*)&Qp[(m * 16 + lr) * 64 + 32 + 8 * lg];
    }

    bf16x8 ones;
#pragma unroll
    for (int e = 0; e < 8; ++e) ones[e] = (short)0x3F80;   // bf16 1.0

    f32x4 acc[2][4];
#pragma unroll
    for (int m = 0; m < 2; ++m)
#pragma unroll
        for (int d0 = 0; d0 < 4; ++d0) acc[m][d0] = zero4;
    f32x4 lacc[2] = {zero4, zero4};

    auto stage = [&](int sbuf, int kt) {
        const size_t kb = (size_t)kt << 6;
#pragma unroll
        for (int i = 0; i < 2; ++i) {
            const int off = i * 4096 + t * 16;
            const int row = off >> 7, cb = off & 127;
            const int scb = cb ^ ((row & 7) << 4);
            GLOAD_LDS16(Kp + ((kb + row) << 7) + scb, (char*)&Ks[sbuf][0] + off);
        }
#pragma unroll
        for (int i = 0; i < 2; ++i) {
            const int off = i * 4096 + t * 16;
            const int row = off >> 7, cb = off & 127;
            const int scb = cb ^ ((row & 7) << 4);
            GLOAD_LDS16(Vp + (size_t)row * 4096 + (kb << 1) + scb, (char*)&Vs[sbuf][0] + off);
        }
    };

    stage(0, 0);
    __syncthreads();
    int buf = 0;
    char* const Pb = (char*)&Pl[wv][0];
    const int psw = lr & 7;   // P chunk swizzle key

    for (int kt = 0; kt < 32; ++kt) {
        if (kt + 1 < 32) stage(buf ^ 1, kt + 1);

        const char* Kb = (const char*)&Ks[buf][0];
        const char* Vb = (const char*)&Vs[buf][0];

        // S^T = mfma(K, Q) per 16-kv tile; exp2 + pack + b64 store into P
#pragma unroll
        for (int n = 0; n < 4; ++n) {
            const int row = n * 16 + lr;
            const int sw = (row & 7) << 4;
            const bf16x8 k0 = *(const bf16x8*)(Kb + row * 128 + ((lg * 16) ^ sw));
            const bf16x8 k1 = *(const bf16x8*)(Kb + row * 128 + ((64 + lg * 16) ^ sw));
#pragma unroll
            for (int m = 0; m < 2; ++m) {
                f32x4 st = MFMA_BF16(k0, qf[m][0], zero4);
                st = MFMA_BF16(k1, qf[m][1], st);
                const float p0 = __builtin_amdgcn_exp2f(st[0]);
                const float p1 = __builtin_amdgcn_exp2f(st[1]);
                const float p2 = __builtin_amdgcn_exp2f(st[2]);
                const float p3 = __builtin_amdgcn_exp2f(st[3]);
                u32x2 pw;
                pw.x = cvt_pk_bf16(p0, p1);
                pw.y = cvt_pk_bf16(p2, p3);
                // P[q=m16+lr][kv=n16+4lg+{0..3}] -> chunk 2n+(lg>>1), byte-in-chunk 8*(lg&1)
                *(u32x2*)(Pb + (m * 16 + lr) * 128 +
                          (((2 * n + (lg >> 1)) ^ psw) << 4) + ((lg & 1) << 3)) = pw;
            }
        }

        // read P as PV A-fragments: lane (lr,lg) gets P[q=m16+lr][kv=hf*32+8lg+{0..7}]
        bf16x8 pf[2][2];
#pragma unroll
        for (int m = 0; m < 2; ++m) {
#pragma unroll
            for (int hf = 0; hf < 2; ++hf) {
                pf[m][hf] = *(const bf16x8*)(Pb + (m * 16 + lr) * 128 +
                                             (((hf * 4 + lg) ^ psw) << 4));
                lacc[m] = MFMA_BF16(pf[m][hf], ones, lacc[m]);   // row-sum of P
            }
        }

        // acc += P V  (setprio: favor MFMA-issuing wave — T5)
        __builtin_amdgcn_s_setprio(1);
#pragma unroll
        for (int hf = 0; hf < 2; ++hf) {
#pragma unroll
            for (int d0 = 0; d0 < 4; ++d0) {
                const int vrow = d0 * 16 + lr;
                const int sw = (vrow & 7) << 4;
                const bf16x8 vf = *(const bf16x8*)(Vb + vrow * 128 + ((hf * 64 + lg * 16) ^ sw));
#pragma unroll
                for (int m = 0; m < 2; ++m)
                    acc[m][d0] = MFMA_BF16(pf[m][hf], vf, acc[m][d0]);
            }
        }
        __builtin_amdgcn_s_setprio(0);

        __syncthreads();
        buf ^= 1;
    }

#pragma unroll
    for (int m = 0; m < 2; ++m) {
#pragma unroll
        for (int d0 = 0; d0 < 4; ++d0) {
#pragma unroll
            for (int r = 0; r < 4; ++r) {
                const int row = q0 + m * 16 + lg * 4 + r;
                const int col = (h << 6) + d0 * 16 + lr;
                AO[(((size_t)b * 2048 + row) << 10) + col] = f2bf(acc[m][d0][r] / lacc[m][r]);
            }
        }
    }
}

extern "C" void kernel_launch(void* const* d_in, const int* in_sizes, int n_in,
                              void* d_out, int out_size, void* d_ws, size_t ws_size,
                              hipStream_t stream) {
    const float* q   = (const float*)d_in[0];
    const float* k   = (const float*)d_in[1];
    const float* v   = (const float*)d_in[2];
    const float* w_q = (const float*)d_in[3];
    const float* b_q = (const float*)d_in[4];
    const float* w_k = (const float*)d_in[5];
    const float* b_k = (const float*)d_in[6];
    const float* w_v = (const float*)d_in[7];
    const float* b_v = (const float*)d_in[8];
    const float* w_o = (const float*)d_in[9];
    const float* b_o = (const float*)d_in[10];
    float* out = (float*)d_out;

    char* ws = (char*)d_ws;
    unsigned short* qb  = (unsigned short*)(ws + 0);          // 8 MB  [4096][1024] bf16
    unsigned short* kb  = (unsigned short*)(ws + 8388608);    // 8 MB
    unsigned short* vb  = (unsigned short*)(ws + 16777216);   // 8 MB
    unsigned short* wtq = (unsigned short*)(ws + 25165824);   // 2 MB  [N][K] bf16
    unsigned short* wtk = (unsigned short*)(ws + 27262976);
    unsigned short* wtv = (unsigned short*)(ws + 29360128);
    unsigned short* wto = (unsigned short*)(ws + 31457280);
    unsigned short* Qh  = (unsigned short*)(ws + 33554432);   // 8 MB  [2][16][2048][64]
    unsigned short* Kh  = (unsigned short*)(ws + 41943040);   // 8 MB
    unsigned short* Vt  = (unsigned short*)(ws + 50331648);   // 8 MB  [2][16][64][2048]
    unsigned short* AO  = (unsigned short*)(ws + 58720256);   // 8 MB  [4096][1024]

    const int n4 = (4096 * 1024) / 4;
    cvt3_kernel<<<dim3(4096, 3), 256, 0, stream>>>(q, k, v, qb, kb, vb, n4);

    wtrans4_kernel<<<dim3(32, 32, 4), dim3(32, 8), 0, stream>>>(
        w_q, w_k, w_v, w_o, wtq, wtk, wtv, wto);

    gemm_qkv_kernel<<<dim3(32, 16, 3), 256, 0, stream>>>(
        qb, kb, vb, wtq, wtk, wtv, b_q, b_k, b_v, Qh, Kh, Vt);

    attn_kernel<<<dim3(16, 16, 2), 256, 0, stream>>>(Qh, Kh, Vt, AO);

    gemm_o_kernel<<<dim3(32, 16), 256, 0, stream>>>(AO, wto, b_o, out);
}